// Round 15
// baseline (48.123 us; speedup 1.0000x reference)
//
#include <hip/hip_runtime.h>
#include <stdint.h>

#define NPIX 4096
#define CIN  256
#define CR   64
#define COUT 512
#define NB   8

typedef _Float16 half8 __attribute__((ext_vector_type(8)));
typedef _Float16 half4 __attribute__((ext_vector_type(4)));
typedef _Float16 half2v __attribute__((ext_vector_type(2)));
typedef float f32x4 __attribute__((ext_vector_type(4)));

// 8-lane sum (groups aligned to 8): quad_perm xor1, xor2, then row_half_mirror.
__device__ __forceinline__ float dpp8_sum(float d) {
  int y;
  y = __builtin_amdgcn_update_dpp(0, __float_as_int(d), 0xB1, 0xF, 0xF, true);
  d += __int_as_float(y);
  y = __builtin_amdgcn_update_dpp(0, __float_as_int(d), 0x4E, 0xF, 0xF, true);
  d += __int_as_float(y);
  y = __builtin_amdgcn_update_dpp(0, __float_as_int(d), 0x141, 0xF, 0xF, true);
  d += __int_as_float(y);
  return d;
}

// split 8 floats into hi/lo f16 halves (v = hi + lo, err ~2^-22)
__device__ __forceinline__ void hilo8(const float4 a, const float4 b,
                                      half8& h, half8& l) {
  const float v[8] = {a.x, a.y, a.z, a.w, b.x, b.y, b.z, b.w};
#pragma unroll
  for (int j = 0; j < 8; ++j) {
    const _Float16 hh = (_Float16)v[j];
    h[j] = hh;
    l[j] = (_Float16)(v[j] - (float)hh);
  }
}

// ---------------------------------------------------------------------------
// K1 (MFMA): feat_h[b,px,ch] (f16 px-major) = sum_k wr[c][k]*x[b,k,px];
// icn[b,px] = rsqrt(sum_c feat^2).  C = Ah*Bh + Ah*Bl + Al*Bh (fp32-class).
// A-fragments gathered DIRECTLY from row-major wr: element [m][kt*32+
// (l>>4)*8+j] -> 8 consecutive floats at wr[m*256 + kt*32 + (l>>4)*8].
// 512 blocks x 8 waves; wave g: nt=g&3 px sub-tile, mth=g>>2 row half.
// Block 0 additionally zeroes the icn/feat_h guard zones (read only by k23).
// ---------------------------------------------------------------------------
__global__ __launch_bounds__(512) void k1_reduce(
    const float* __restrict__ x, const float* __restrict__ wr,
    _Float16* __restrict__ feat_h, float* __restrict__ icn)
{
  const int blk = blockIdx.x;             // 512 = b(3b) | seg(6b)
  const int b = blk >> 6, seg = blk & 63;
  const int t = threadIdx.x, lane = t & 63;
  const int g = __builtin_amdgcn_readfirstlane((int)t >> 6);  // 0..7
  const int nt = g & 3, mth = g >> 2;
  const int col = lane & 15, krow = lane >> 4;

  if (blk == 0) {                         // zero guards for k23's staging
    if (t < 8) icn[(int)t - 8] = 0.f;                       // icn head
    if (t >= 8 && t < 80) icn[NB * NPIX + (int)t - 8] = 0.f; // icn tail (72)
    float* fgh = (float*)feat_h;
    if (t < 256) fgh[(int)t - 256] = 0.f;                   // feat head 512 f16
    float* fgt = (float*)feat_h + (size_t)NB * NPIX * 32;   // = f16 count / 2
    if (t < 256) fgt[t] = 0.f;                              // feat tail 512 f16
  }

  const float* xb = x + (size_t)b * CIN * NPIX + seg * 64 + nt * 16 + col;
  const float* wrm0 = wr + (size_t)((mth * 2 + 0) * 16 + col) * CIN + krow * 8;
  const float* wrm1 = wr + (size_t)((mth * 2 + 1) * 16 + col) * CIN + krow * 8;

  f32x4 c0 = {0.f, 0.f, 0.f, 0.f};
  f32x4 c1 = {0.f, 0.f, 0.f, 0.f};

#pragma unroll
  for (int kt = 0; kt < 8; ++kt) {
    // B-frag from x: k = kt*32 + krow*8 + j, n = col
    half8 Bh, Bl;
    const float* xk = xb + (size_t)(kt * 32 + krow * 8) * NPIX;
#pragma unroll
    for (int j = 0; j < 8; ++j) {
      const float v = xk[(size_t)j * NPIX];
      const _Float16 h = (_Float16)v;
      Bh[j] = h;
      Bl[j] = (_Float16)(v - (float)h);
    }
    // A-frags directly from wr (32 B contiguous per lane, L2-hot)
    half8 Ah0, Al0, Ah1, Al1;
    hilo8(*(const float4*)(wrm0 + kt * 32), *(const float4*)(wrm0 + kt * 32 + 4),
          Ah0, Al0);
    hilo8(*(const float4*)(wrm1 + kt * 32), *(const float4*)(wrm1 + kt * 32 + 4),
          Ah1, Al1);
    c0 = __builtin_amdgcn_mfma_f32_16x16x32_f16(Ah0, Bh, c0, 0, 0, 0);
    c0 = __builtin_amdgcn_mfma_f32_16x16x32_f16(Ah0, Bl, c0, 0, 0, 0);
    c0 = __builtin_amdgcn_mfma_f32_16x16x32_f16(Al0, Bh, c0, 0, 0, 0);
    c1 = __builtin_amdgcn_mfma_f32_16x16x32_f16(Ah1, Bh, c1, 0, 0, 0);
    c1 = __builtin_amdgcn_mfma_f32_16x16x32_f16(Ah1, Bl, c1, 0, 0, 0);
    c1 = __builtin_amdgcn_mfma_f32_16x16x32_f16(Al1, Bh, c1, 0, 0, 0);
  }

  // C layout (HW-verified): col = lane&15, row = krow*4 + r (consecutive ch)
  const int px = seg * 64 + nt * 16 + col;
  _Float16* fb = feat_h + ((size_t)b * NPIX + px) * 64;
  const int ch0 = mth * 32 + krow * 4;
  half4 v0, v1;
  float p = 0.f;
#pragma unroll
  for (int r = 0; r < 4; ++r) {
    v0[r] = (_Float16)c0[r];
    v1[r] = (_Float16)c1[r];
    p = fmaf(c0[r], c0[r], p);
    p = fmaf(c1[r], c1[r], p);
  }
  *(half4*)(fb + ch0) = v0;
  *(half4*)(fb + ch0 + 16) = v1;

  p += __shfl_xor(p, 16);
  p += __shfl_xor(p, 32);

  __shared__ float cn[8][16];
  if (lane < 16) cn[g][lane] = p;
  __syncthreads();
  if (t < 64) {
    const int nt2 = t >> 4, c16 = t & 15;
    const float ss = cn[nt2][c16] + cn[nt2 + 4][c16];
    icn[b * NPIX + seg * 64 + t] = rsqrtf(fmaxf(ss, 1e-16f));
  }
}

// ---------------------------------------------------------------------------
// K23: fused correlation-softmax-attention (f16 packed) + projection (MFMA).
// Block = (b,h) row of 64 px, 512 thr (8 waves). XCD map b=blk&7.
//
// Staging: feat_h px-major -> 72px x 64ch row tile is one contiguous range;
// thread t copies h8 at rowb+t*8 (+ tail) -> coalesced loads, bank-balanced
// b128 writes. T14 split: LOAD before compute, WRITE after. icn row staged
// alongside (cnS).
//
// Phase A per neighbor: 1x ds_read_b128, 4x v_dot2_f32_f16 (f32 acc), DPP
// 8-lane combine, sim = d*icnc*icnk (no fmax/rcp), one-pass softmax
// (sim<=1 -> exp<=e), 4x v_pk_fma_f16 into 2 alternating h2 accumulators.
// OOB rows skipped (l+=7); OOB cols select-masked; guard bytes zeroed by k1.
//
// Phase B: corr -> f16 corrH[px][64k] XOR-swizzled; A-frags gathered directly
// from row-major wp (8 consecutive floats per lane) and hoisted to registers;
// 2x mfma_f32_16x16x32_f16 per 16x16 out tile. (layouts HW-verified r11/r12)
// ---------------------------------------------------------------------------
__global__ __launch_bounds__(512, 4) void k23_fused(
    const _Float16* __restrict__ feat_h, const float* __restrict__ icn,
    const float* __restrict__ wp, float* __restrict__ out)
{
  const int blk = blockIdx.x;          // 512
  const int b = blk & 7, h = blk >> 3; // XCD-aware: xcd = blk % 8 = b
  const int t = threadIdx.x;
  const int lane = t & 63;
  const int g = __builtin_amdgcn_readfirstlane((int)t >> 6);  // 0..7
  const int w = t >> 3;                // px col 0..63
  const int cb = (t & 7) * 8;          // channel base for this lane
  const int px = h * 64 + w;
  const int gpx = b * NPIX + px;

  const float* cnb = icn + b * NPIX;

  __shared__ __align__(16) _Float16 fs[2][72][72];   // 20736 B, 144 B rows
  __shared__ float cnS[2][80];                       // 640 B
  __shared__ __align__(16) _Float16 corrH[4096];     // 8192 B

  half8 rS0, rS1;
  float rc = 0.f;

  auto LOAD = [&](int ar) {
    const long rowb = ((long)b * NPIX + ar * 64 - 4) * 64;  // f16 units
    rS0 = *(const half8*)(feat_h + rowb + (long)t * 8);     // contiguous
    if (t < 64) rS1 = *(const half8*)(feat_h + rowb + (long)(512 + t) * 8);
    if (t < 72) rc = cnb[ar * 64 - 4 + t];
  };
  auto WRITE = [&](int bufi) {
    *(half8*)&fs[bufi][t >> 3][(t & 7) * 8] = rS0;
    if (t < 64) *(half8*)&fs[bufi][64 + (t >> 3)][(t & 7) * 8] = rS1;
    if (t < 72) cnS[bufi][t] = rc;
  };

  // center features (f16, contiguous 16 B per lane)
  half2v fc2[4];
  {
    const half8 fcv = *(const half8*)(feat_h + ((size_t)b * NPIX + px) * 64 + cb);
#pragma unroll
    for (int i = 0; i < 4; ++i) { fc2[i][0] = fcv[2*i]; fc2[i][1] = fcv[2*i+1]; }
  }
  const float icnc = icn[gpx];

  half2v accA[4], accB[4];
#pragma unroll
  for (int i = 0; i < 4; ++i) {
    accA[i] = (half2v)(_Float16)0.f;
    accB[i] = (half2v)(_Float16)0.f;
  }

  const int lo = (h - 3 < 0) ? 0 : h - 3;
  const int hi = (h + 3 > 63) ? 63 : h + 3;
  float l = 7.0f * (float)(6 - (hi - lo));   // skipped rows: 7 x exp(0)

  LOAD(lo);
  WRITE(0);
  __syncthreads();

  int buf = 0;
  for (int ar = lo; ar <= hi; ++ar) {
    if (ar < hi) LOAD(ar + 1);               // issue early: hides under compute
#pragma unroll
    for (int dx = -3; dx <= 3; ++dx) {
      const int j = w + 4 + dx;
      const half8 nv = *(const half8*)&fs[buf][j][cb];
      half2v n0, n1, n2, n3;
      n0[0] = nv[0]; n0[1] = nv[1];
      n1[0] = nv[2]; n1[1] = nv[3];
      n2[0] = nv[4]; n2[1] = nv[5];
      n3[0] = nv[6]; n3[1] = nv[7];
      float d = 0.f;
      d = __builtin_amdgcn_fdot2(fc2[0], n0, d, false);
      d = __builtin_amdgcn_fdot2(fc2[1], n1, d, false);
      d = __builtin_amdgcn_fdot2(fc2[2], n2, d, false);
      d = __builtin_amdgcn_fdot2(fc2[3], n3, d, false);
      d = dpp8_sum(d);                 // 8-lane reduce, VALU-only
      const float icnk = cnS[buf][j];  // 0 on guard -> sim 0
      float sim = d * icnc * icnk;
      const bool valid = (unsigned)(w + dx) < 64u;
      sim = valid ? sim : 0.f;         // select: NaN/Inf-safe
      const float p = __expf(sim);     // sim <= 1 -> p <= e
      l += p;
      const float pv = valid ? p : 0.f;
      const _Float16 ph = (_Float16)pv;
      half2v ph2; ph2[0] = ph; ph2[1] = ph;
      if (dx & 1) {
        accA[0] = ph2 * n0 + accA[0];
        accA[1] = ph2 * n1 + accA[1];
        accA[2] = ph2 * n2 + accA[2];
        accA[3] = ph2 * n3 + accA[3];
      } else {
        accB[0] = ph2 * n0 + accB[0];
        accB[1] = ph2 * n1 + accB[1];
        accB[2] = ph2 * n2 + accB[2];
        accB[3] = ph2 * n3 + accB[3];
      }
    }
    if (ar < hi) WRITE(buf ^ 1);             // vmcnt waits here, not earlier
    __syncthreads();
    buf ^= 1;
  }

  // combine f16 partials in f32, normalize, write f16 corrH (XOR-swizzled)
  {
    const float inv = __builtin_amdgcn_rcpf(l);
    half8 hv;
#pragma unroll
    for (int i = 0; i < 4; ++i) {
      const float a0 = (float)accA[i][0] + (float)accB[i][0];
      const float a1 = (float)accA[i][1] + (float)accB[i][1];
      hv[2*i]   = (_Float16)(a0 * inv);
      hv[2*i+1] = (_Float16)(a1 * inv);
    }
    const int wbyte = (w * 128 + (cb << 1)) ^ ((w & 7) << 4);
    *(half8*)((char*)corrH + wbyte) = hv;
  }

  // hoist + convert phase-B A-frags directly from wp (row-major, L2-hot):
  // element [o][k] with o = g*64+ot*16+(lane&15), k = kt*32+(lane>>4)*8+j
  // -> 8 consecutive floats. 8 frags = 32 VGPR.
  half8 Af[8];
#pragma unroll
  for (int ot = 0; ot < 4; ++ot)
#pragma unroll
    for (int k2 = 0; k2 < 2; ++k2) {
      const float* wpp = wp + (size_t)(g * 64 + ot * 16 + (lane & 15)) * 64
                       + k2 * 32 + (lane >> 4) * 8;
      const float4 lo4 = *(const float4*)wpp;
      const float4 hi4 = *(const float4*)(wpp + 4);
      half8 a;
      a[0] = (_Float16)lo4.x; a[1] = (_Float16)lo4.y;
      a[2] = (_Float16)lo4.z; a[3] = (_Float16)lo4.w;
      a[4] = (_Float16)hi4.x; a[5] = (_Float16)hi4.y;
      a[6] = (_Float16)hi4.z; a[7] = (_Float16)hi4.w;
      Af[ot * 2 + k2] = a;
    }
  __syncthreads();

  // ---- Phase B: MFMA proj. Wave g -> outs [g*64, g*64+64) x 64 px.
  float* outb = out + ((size_t)b * COUT + g * 64) * NPIX + h * 64;
#pragma unroll
  for (int pt = 0; pt < 4; ++pt) {
    half8 Bf0, Bf1;
    {
      const int pxl = pt * 16 + (lane & 15);
      const int sw = (pxl & 7) << 4;
      const int rowb = pxl * 128 + ((lane >> 4) << 4);
      Bf0 = *(const half8*)((const char*)corrH + (rowb ^ sw));
      Bf1 = *(const half8*)((const char*)corrH + ((rowb + 64) ^ sw));
    }
#pragma unroll
    for (int ot = 0; ot < 4; ++ot) {
      f32x4 c = {0.f, 0.f, 0.f, 0.f};
      c = __builtin_amdgcn_mfma_f32_16x16x32_f16(Af[ot * 2 + 0], Bf0, c, 0, 0, 0);
      c = __builtin_amdgcn_mfma_f32_16x16x32_f16(Af[ot * 2 + 1], Bf1, c, 0, 0, 0);
      float* op = outb + (size_t)(ot * 16 + ((lane >> 4) << 2)) * NPIX
                       + pt * 16 + (lane & 15);
#pragma unroll
      for (int r = 0; r < 4; ++r) op[(size_t)r * NPIX] = c[r];
    }
  }
}

// ---------------------------------------------------------------------------
extern "C" void kernel_launch(void* const* d_in, const int* in_sizes, int n_in,
                              void* d_out, int out_size, void* d_ws, size_t ws_size,
                              hipStream_t stream)
{
  const float* x  = (const float*)d_in[0];
  const float* wr = (const float*)d_in[1];
  const float* wp = (const float*)d_in[2];
  float* out = (float*)d_out;

  // ws layout (float-slots):
  //   [8 icn head guard] icn[8*4096] [72 icn tail guard]
  //   [256 feat head guard] feat_h[8*4096*64 f16 = 1048576 float-slots]
  //   [256 feat tail guard]
  // guards zeroed by k1 block 0 each call (k23 reads them after the kernel
  // boundary). Total ~4.1 MiB.
  float* ws = (float*)d_ws;
  float* icn = ws + 8;
  _Float16* feat_h = (_Float16*)(ws + 8 + NB * NPIX + 72 + 256);

  hipLaunchKernelGGL(k1_reduce, dim3(512), dim3(512), 0, stream, x, wr, feat_h, icn);
  hipLaunchKernelGGL(k23_fused, dim3(512), dim3(512), 0, stream, feat_h, icn, wp, out);
}

// Round 16
// 40.477 us; speedup vs baseline: 1.1889x; 1.1889x over previous
//
#include <hip/hip_runtime.h>
#include <stdint.h>

#define NPIX 4096
#define CIN  256
#define CR   64
#define COUT 512
#define NB   8
#define CG   256     // icn guard floats each side (also covers feat_h head)
#define FT   128     // feat_h tail guard (floats; covers +4 px overhang)

typedef _Float16 half8 __attribute__((ext_vector_type(8)));
typedef _Float16 half4 __attribute__((ext_vector_type(4)));
typedef _Float16 half2v __attribute__((ext_vector_type(2)));
typedef float f32x4 __attribute__((ext_vector_type(4)));

// 8-lane sum (groups aligned to 8): quad_perm xor1, xor2, then row_half_mirror.
__device__ __forceinline__ float dpp8_sum(float d) {
  int y;
  y = __builtin_amdgcn_update_dpp(0, __float_as_int(d), 0xB1, 0xF, 0xF, true);
  d += __int_as_float(y);
  y = __builtin_amdgcn_update_dpp(0, __float_as_int(d), 0x4E, 0xF, 0xF, true);
  d += __int_as_float(y);
  y = __builtin_amdgcn_update_dpp(0, __float_as_int(d), 0x141, 0xF, 0xF, true);
  d += __int_as_float(y);
  return d;
}

// ---------------------------------------------------------------------------
// K0: pack w_reduce into hi/lo fp16 A-fragments (k1 MFMA), wp into fp16
// A-fragments (k23 phase B), zero guard zones.  (r13 structure — pre-packing
// amortizes the conversion once; r14's inline version cost ~9 us redundant VALU)
// A-frag layout (16x16x32, HW-verified r11): lane l holds 8 elems
// A[m = l&15][k = kt*32 + (l>>4)*8 + j], stored at frag*512 + l*8 + j.
// ---------------------------------------------------------------------------
__global__ __launch_bounds__(256) void k0_prep(
    const float* __restrict__ wr, const float* __restrict__ wp,
    _Float16* __restrict__ wrAh, _Float16* __restrict__ wrAl,
    _Float16* __restrict__ wpH,
    float* __restrict__ icnG, float* __restrict__ featTail)
{
  const int tid = blockIdx.x * 256 + threadIdx.x;
  if (tid < 16384) {                          // wr[64][256] -> hi/lo A-frags
    const int j = tid & 7, l = (tid >> 3) & 63;
    const int kt = (tid >> 9) & 7, mt = tid >> 12;
    const int m = mt * 16 + (l & 15);
    const int k = kt * 32 + (l >> 4) * 8 + j;
    const float v = wr[m * CIN + k];
    const _Float16 h = (_Float16)v;
    wrAh[tid] = h;
    wrAl[tid] = (_Float16)(v - (float)h);
  } else if (tid < 16384 + COUT * CR) {       // wp[512][64] -> A-frags f16
    const int fi = tid - 16384;
    const int j = fi & 7, l = (fi >> 3) & 63;
    const int kt = (fi >> 9) & 1, ot = (fi >> 10) & 3, g = fi >> 12;
    const int o = g * 64 + ot * 16 + (l & 15);
    const int k = kt * 32 + (l >> 4) * 8 + j;
    wpH[fi] = (_Float16)wp[o * CR + k];
  } else {
    const int gi = tid - (16384 + COUT * CR);
    if (gi < CG)               icnG[gi] = 0.f;                         // head
    else if (gi < 2 * CG)      icnG[CG + NB * NPIX + (gi - CG)] = 0.f; // tail
    else if (gi < 2 * CG + FT) featTail[gi - 2 * CG] = 0.f;            // feat tail
  }
}

// ---------------------------------------------------------------------------
// K1 (MFMA): feat_h[b,px,ch] (f16, px-major) = sum_k wr[c][k]*x[b,k,px];
// icn (f32) = rsqrt(max(sum_c feat^2, 1e-16)).
// C = Ah*Bh + Ah*Bl + Al*Bh (fp32-class).  512 blocks x 8 waves.
// ---------------------------------------------------------------------------
__global__ __launch_bounds__(512) void k1_reduce(
    const float* __restrict__ x,
    const _Float16* __restrict__ wrAh, const _Float16* __restrict__ wrAl,
    _Float16* __restrict__ feat_h, float* __restrict__ icn)
{
  const int blk = blockIdx.x;             // 512 = b(3b) | seg(6b)
  const int b = blk >> 6, seg = blk & 63;
  const int t = threadIdx.x, lane = t & 63;
  const int g = __builtin_amdgcn_readfirstlane((int)t >> 6);  // 0..7
  const int nt = g & 3, mth = g >> 2;
  const int col = lane & 15, krow = lane >> 4;

  const float* xb = x + (size_t)b * CIN * NPIX + seg * 64 + nt * 16 + col;

  f32x4 c0 = {0.f, 0.f, 0.f, 0.f};
  f32x4 c1 = {0.f, 0.f, 0.f, 0.f};

#pragma unroll
  for (int kt = 0; kt < 8; ++kt) {
    half8 Bh, Bl;
    const float* xk = xb + (size_t)(kt * 32 + krow * 8) * NPIX;
#pragma unroll
    for (int j = 0; j < 8; ++j) {
      const float v = xk[(size_t)j * NPIX];
      const _Float16 h = (_Float16)v;
      Bh[j] = h;
      Bl[j] = (_Float16)(v - (float)h);
    }
    const int fi0 = ((mth * 2 + 0) * 8 + kt) * 512 + lane * 8;
    const int fi1 = ((mth * 2 + 1) * 8 + kt) * 512 + lane * 8;
    const half8 Ah0 = *(const half8*)(wrAh + fi0);
    const half8 Al0 = *(const half8*)(wrAl + fi0);
    const half8 Ah1 = *(const half8*)(wrAh + fi1);
    const half8 Al1 = *(const half8*)(wrAl + fi1);
    c0 = __builtin_amdgcn_mfma_f32_16x16x32_f16(Ah0, Bh, c0, 0, 0, 0);
    c0 = __builtin_amdgcn_mfma_f32_16x16x32_f16(Ah0, Bl, c0, 0, 0, 0);
    c0 = __builtin_amdgcn_mfma_f32_16x16x32_f16(Al0, Bh, c0, 0, 0, 0);
    c1 = __builtin_amdgcn_mfma_f32_16x16x32_f16(Ah1, Bh, c1, 0, 0, 0);
    c1 = __builtin_amdgcn_mfma_f32_16x16x32_f16(Ah1, Bl, c1, 0, 0, 0);
    c1 = __builtin_amdgcn_mfma_f32_16x16x32_f16(Al1, Bh, c1, 0, 0, 0);
  }

  // C layout (HW-verified): col = lane&15, row = krow*4 + r (consecutive ch)
  const int px = seg * 64 + nt * 16 + col;
  _Float16* fb = feat_h + ((size_t)b * NPIX + px) * 64;
  const int ch0 = mth * 32 + krow * 4;
  half4 v0, v1;
  float p = 0.f;
#pragma unroll
  for (int r = 0; r < 4; ++r) {
    v0[r] = (_Float16)c0[r];
    v1[r] = (_Float16)c1[r];
    p = fmaf(c0[r], c0[r], p);
    p = fmaf(c1[r], c1[r], p);
  }
  *(half4*)(fb + ch0) = v0;
  *(half4*)(fb + ch0 + 16) = v1;

  p += __shfl_xor(p, 16);
  p += __shfl_xor(p, 32);

  __shared__ float cn[8][16];
  if (lane < 16) cn[g][lane] = p;
  __syncthreads();
  if (t < 64) {
    const int nt2 = t >> 4, c16 = t & 15;
    const float ss = cn[nt2][c16] + cn[nt2 + 4][c16];
    icn[b * NPIX + seg * 64 + t] = rsqrtf(fmaxf(ss, 1e-16f));
  }
}

// ---------------------------------------------------------------------------
// K23: fused correlation-softmax-attention (f16 packed) + projection (MFMA).
// Block = (b,h) row of 64 px, 512 thr (8 waves). XCD map b=blk&7.
// r13 structure; inner loop uses icn (sim = d*icnc*icnk, no fmax/rcp).
// ---------------------------------------------------------------------------
__global__ __launch_bounds__(512, 4) void k23_fused(
    const _Float16* __restrict__ feat_h, const float* __restrict__ icn,
    const _Float16* __restrict__ wpH, float* __restrict__ out)
{
  const int blk = blockIdx.x;          // 512
  const int b = blk & 7, h = blk >> 3; // XCD-aware: xcd = blk % 8 = b
  const int t = threadIdx.x;
  const int lane = t & 63;
  const int g = __builtin_amdgcn_readfirstlane((int)t >> 6);  // 0..7
  const int w = t >> 3;                // px col 0..63
  const int cb = (t & 7) * 8;          // channel base for this lane
  const int px = h * 64 + w;
  const int gpx = b * NPIX + px;

  const float* cnb = icn + b * NPIX;

  __shared__ __align__(16) _Float16 fs[2][72][72];   // 20736 B, 144 B rows
  __shared__ float cnS[2][80];                       // 640 B
  __shared__ __align__(16) _Float16 corrH[4096];     // 8192 B

  half8 rS0, rS1;
  float rc = 0.f;

  auto LOAD = [&](int ar) {
    const long rowb = ((long)b * NPIX + ar * 64 - 4) * 64;  // f16 units
    rS0 = *(const half8*)(feat_h + rowb + (long)t * 8);     // contiguous
    if (t < 64) rS1 = *(const half8*)(feat_h + rowb + (long)(512 + t) * 8);
    if (t < 72) rc = cnb[ar * 64 - 4 + t];
  };
  auto WRITE = [&](int bufi) {
    *(half8*)&fs[bufi][t >> 3][(t & 7) * 8] = rS0;
    if (t < 64) *(half8*)&fs[bufi][64 + (t >> 3)][(t & 7) * 8] = rS1;
    if (t < 72) cnS[bufi][t] = rc;
  };

  // center features (f16, contiguous 16 B per lane)
  half2v fc2[4];
  {
    const half8 fcv = *(const half8*)(feat_h + ((size_t)b * NPIX + px) * 64 + cb);
#pragma unroll
    for (int i = 0; i < 4; ++i) { fc2[i][0] = fcv[2*i]; fc2[i][1] = fcv[2*i+1]; }
  }
  const float icnc = icn[gpx];

  half2v accA[4], accB[4];
#pragma unroll
  for (int i = 0; i < 4; ++i) {
    accA[i] = (half2v)(_Float16)0.f;
    accB[i] = (half2v)(_Float16)0.f;
  }

  const int lo = (h - 3 < 0) ? 0 : h - 3;
  const int hi = (h + 3 > 63) ? 63 : h + 3;
  float l = 7.0f * (float)(6 - (hi - lo));   // skipped rows: 7 x exp(0)

  LOAD(lo);
  WRITE(0);
  __syncthreads();

  int buf = 0;
  for (int ar = lo; ar <= hi; ++ar) {
    if (ar < hi) LOAD(ar + 1);               // issue early: hides under compute
#pragma unroll
    for (int dx = -3; dx <= 3; ++dx) {
      const int j = w + 4 + dx;
      const half8 nv = *(const half8*)&fs[buf][j][cb];
      half2v n0, n1, n2, n3;
      n0[0] = nv[0]; n0[1] = nv[1];
      n1[0] = nv[2]; n1[1] = nv[3];
      n2[0] = nv[4]; n2[1] = nv[5];
      n3[0] = nv[6]; n3[1] = nv[7];
      float d = 0.f;
      d = __builtin_amdgcn_fdot2(fc2[0], n0, d, false);
      d = __builtin_amdgcn_fdot2(fc2[1], n1, d, false);
      d = __builtin_amdgcn_fdot2(fc2[2], n2, d, false);
      d = __builtin_amdgcn_fdot2(fc2[3], n3, d, false);
      d = dpp8_sum(d);                 // 8-lane reduce, VALU-only
      const float icnk = cnS[buf][j];  // 0 on guard -> sim 0
      float sim = d * icnc * icnk;
      const bool valid = (unsigned)(w + dx) < 64u;
      sim = valid ? sim : 0.f;         // select: NaN/Inf-safe
      const float p = __expf(sim);     // sim <= 1 -> p <= e
      l += p;
      const float pv = valid ? p : 0.f;
      const _Float16 ph = (_Float16)pv;
      half2v ph2; ph2[0] = ph; ph2[1] = ph;
      if (dx & 1) {
        accA[0] = ph2 * n0 + accA[0];
        accA[1] = ph2 * n1 + accA[1];
        accA[2] = ph2 * n2 + accA[2];
        accA[3] = ph2 * n3 + accA[3];
      } else {
        accB[0] = ph2 * n0 + accB[0];
        accB[1] = ph2 * n1 + accB[1];
        accB[2] = ph2 * n2 + accB[2];
        accB[3] = ph2 * n3 + accB[3];
      }
    }
    if (ar < hi) WRITE(buf ^ 1);             // vmcnt waits here, not earlier
    __syncthreads();
    buf ^= 1;
  }

  // combine f16 partials in f32, normalize, write f16 corrH (XOR-swizzled)
  {
    const float inv = __builtin_amdgcn_rcpf(l);
    half8 hv;
#pragma unroll
    for (int i = 0; i < 4; ++i) {
      const float a0 = (float)accA[i][0] + (float)accB[i][0];
      const float a1 = (float)accA[i][1] + (float)accB[i][1];
      hv[2*i]   = (_Float16)(a0 * inv);
      hv[2*i+1] = (_Float16)(a1 * inv);
    }
    const int wbyte = (w * 128 + (cb << 1)) ^ ((w & 7) << 4);
    *(half8*)((char*)corrH + wbyte) = hv;
  }
  __syncthreads();

  // ---- Phase B: MFMA proj. Wave g -> outs [g*64, g*64+64) x 64 px.
  const _Float16* wA = wpH + (size_t)g * 4096;
  float* outb = out + ((size_t)b * COUT + g * 64) * NPIX + h * 64;
#pragma unroll
  for (int pt = 0; pt < 4; ++pt) {
    half8 Bf0, Bf1;
    {
      const int pxl = pt * 16 + (lane & 15);
      const int sw = (pxl & 7) << 4;
      const int rowb = pxl * 128 + ((lane >> 4) << 4);
      Bf0 = *(const half8*)((const char*)corrH + (rowb ^ sw));
      Bf1 = *(const half8*)((const char*)corrH + ((rowb + 64) ^ sw));
    }
#pragma unroll
    for (int ot = 0; ot < 4; ++ot) {
      f32x4 c = {0.f, 0.f, 0.f, 0.f};
      const half8 A0 = *(const half8*)(wA + (ot * 2 + 0) * 512 + lane * 8);
      const half8 A1 = *(const half8*)(wA + (ot * 2 + 1) * 512 + lane * 8);
      c = __builtin_amdgcn_mfma_f32_16x16x32_f16(A0, Bf0, c, 0, 0, 0);
      c = __builtin_amdgcn_mfma_f32_16x16x32_f16(A1, Bf1, c, 0, 0, 0);
      float* op = outb + (size_t)(ot * 16 + ((lane >> 4) << 2)) * NPIX
                       + pt * 16 + (lane & 15);
#pragma unroll
      for (int r = 0; r < 4; ++r) op[(size_t)r * NPIX] = c[r];
    }
  }
}

// ---------------------------------------------------------------------------
extern "C" void kernel_launch(void* const* d_in, const int* in_sizes, int n_in,
                              void* d_out, int out_size, void* d_ws, size_t ws_size,
                              hipStream_t stream)
{
  const float* x  = (const float*)d_in[0];
  const float* wr = (const float*)d_in[1];
  const float* wp = (const float*)d_in[2];
  float* out = (float*)d_out;

  // ws layout (float-slots):
  //   wrAh[8192] | wrAl[8192] | wpH[16384] |
  //   [CG] icn[8*4096] [CG] | feat_h[8*4096*64 f16 = 1M float-slots] | [FT]
  // feat_h head overhang (-4 px = 512 B) covered by icn tail guard (1 KB);
  // tail overhang (+4 px) covered by FT guard.
  float* ws = (float*)d_ws;
  _Float16* wrAh  = (_Float16*)ws;
  _Float16* wrAl  = (_Float16*)(ws + 8192);
  _Float16* wpH   = (_Float16*)(ws + 16384);
  float* icnG     = ws + 32768;             // guarded region base
  float* icn      = icnG + CG;
  _Float16* feat_h = (_Float16*)(icn + NB * NPIX + CG);
  float* featTail = (float*)(feat_h + (size_t)NB * NPIX * 64);

  hipLaunchKernelGGL(k0_prep,   dim3(195), dim3(256), 0, stream, wr, wp, wrAh, wrAl, wpH, icnG, featTail);
  hipLaunchKernelGGL(k1_reduce, dim3(512), dim3(512), 0, stream, x, wrAh, wrAl, feat_h, icn);
  hipLaunchKernelGGL(k23_fused, dim3(512), dim3(512), 0, stream, feat_h, icn, wpH, out);
}